// Round 11
// baseline (225.446 us; speedup 1.0000x reference)
//
#include <hip/hip_runtime.h>
#include <math.h>

// ModernBERT sliding-window attention.
// B=4 S=2048 H=12 D=64 HIDDEN=768 WINDOW=64 (|i-j|<=64 allowed).
// R18 (= R17 hardened; R17 bench was an infra failure): fuse hidden
// f32->bf16 cvt INTO gemm_qkv's A-staging (reg-stage: 2x dwordx4 f32 ->
// 4x v_cvt_pk_bf16_f32 -> ds_write_b128), B stays gload_lds ping-pong.
// Hardening vs R17: plain __launch_bounds__(512) (the ",8" variant capped
// VGPR at 64 < ~80 live -> spill risk, R11 failure mode); afn initialized.
// cvt shrinks to weights-only. nt = R13-exact; attn_v4 = R14-exact.
// Pipeline: [cvt_wts] -> [GEMM qkv(f32 A) + RoPE] -> [MFMA attn] -> [GEMM out].

typedef __attribute__((ext_vector_type(8))) short short8;
typedef __attribute__((ext_vector_type(4))) float floatx4;

constexpr int kB = 4;
constexpr int kS = 2048;
constexpr int kH = 12;
constexpr int kD = 64;
constexpr int kHidden = 768;
constexpr int kQKV = 3 * kHidden;  // 2304

__device__ __forceinline__ unsigned short f2bf(float f) {
  union { float f; unsigned int u; } x; x.f = f;
  unsigned int r = (x.u + 0x7fffu + ((x.u >> 16) & 1u)) >> 16;  // RNE
  return (unsigned short)r;
}

// weights-only conversion (hidden is converted inside gemm_qkv now)
__global__ __launch_bounds__(256) void cvt_wts(
    const float* __restrict__ wqkv, const float* __restrict__ wo,
    unsigned short* __restrict__ wqb, unsigned short* __restrict__ wob) {
  constexpr int n2 = kQKV * kHidden / 4;         // 442368
  constexpr int n3 = kHidden * kHidden / 4;      // 147456
  int i = blockIdx.x * 256 + threadIdx.x;
  const float* src;
  unsigned short* dst;
  if (i < n2) {
    src = wqkv; dst = wqb;
  } else {
    i -= n2; if (i >= n3) return; src = wo; dst = wob;
  }
  const float4 v = ((const float4*)src)[i];
  ushort4 o;
  o.x = f2bf(v.x); o.y = f2bf(v.y); o.z = f2bf(v.z); o.w = f2bf(v.w);
  ((ushort4*)dst)[i] = o;
}

__device__ __forceinline__ void gload_lds16(const unsigned short* g, unsigned short* l) {
  __builtin_amdgcn_global_load_lds(
      (const __attribute__((address_space(1))) unsigned int*)g,
      (__attribute__((address_space(3))) unsigned int*)l, 16, 0, 0);
}

// ---------------------------------------------------------------------------
// GEMM1: qkv = hidden(f32!) @ Wqkv^T with fused cvt + RoPE epilogue.
// cols<768 -> Qr (RoPE, *0.125, bf16 [b,h,s,d]); [768,1536) -> Kr (RoPE, bf16
// [b,h,s,d]); >=1536 -> Vt (bf16 TRANSPOSED [b,h,d,s]).
// 8 waves, 128x128 tile, ping-pong half-K (24 phases). Per phase per thread:
// {load next A-chunk as 8 f32 (2x dwordx4); gload_lds next B; vmcnt(3)
// retires cur A regs + cur B (oldest three in any issue order); cvt_pk cur A
// -> ds_write_b128; lgkmcnt(0); barrier; 2+4 ds_read_b128; 8 MFMA; barrier}.
// ---------------------------------------------------------------------------
__global__ __launch_bounds__(512) void gemm_qkv(
    const float* __restrict__ A32,          // [M][768] f32 hidden
    const unsigned short* __restrict__ B,   // [2304][768] bf16 Wqkv
    const float* __restrict__ cosp, const float* __restrict__ sinp,
    unsigned short* __restrict__ Qr, unsigned short* __restrict__ Kr,
    unsigned short* __restrict__ Vt) {
  constexpr int K = kHidden;
  constexpr int NP = 2 * (K / 64);          // 24 phases
  __shared__ unsigned short SH[128 * 136];  // 34816 B
  unsigned short* Ah0 = SH;                 // 128x32 bf16 (8 KB)
  unsigned short* Ah1 = SH + 4096;
  unsigned short* Bh0 = SH + 8192;
  unsigned short* Bh1 = SH + 12288;

  const int tid = threadIdx.x;    // 0..511
  const int lane = tid & 63;
  const int wave = tid >> 6;      // 0..7
  const int m0 = blockIdx.x * 128;
  const int n0 = blockIdx.y * 128;

  const int sc = wave * 64 + lane;        // 0..511
  const int srow = sc >> 2;               // 0..127
  const int sgc = ((sc & 3) ^ ((srow >> 1) & 3)) * 8;  // elem offset in half
  const int ldsOff = sc * 8;              // shorts
  const float* gA32 = A32 + (size_t)(m0 + srow) * K + sgc;
  const unsigned short* gB0 = B + (size_t)(n0 + srow) * K + sgc;

  const int wm = wave >> 1, wn = wave & 1;   // 4 row-groups x 2 col-groups
  const int mr = wm * 32 + (lane & 15);
  const int nr = wn * 64 + (lane & 15);
  const int kq = lane >> 4;

  int aOff[2], bOff[4];
#pragma unroll
  for (int i = 0; i < 2; i++) {
    const int r = mr + i * 16;
    aOff[i] = (r * 4 + (kq ^ ((r >> 1) & 3))) * 8;
  }
#pragma unroll
  for (int j = 0; j < 4; j++) {
    const int r = nr + j * 16;
    bOff[j] = (r * 4 + (kq ^ ((r >> 1) & 3))) * 8;
  }

  floatx4 acc[2][4];
#pragma unroll
  for (int i = 0; i < 2; i++)
#pragma unroll
    for (int j = 0; j < 4; j++) acc[i][j] = (floatx4)(0.f);

  // prologue: A(0) f32 chunk into regs, B(0) into LDS
  float4 afc0 = *(const float4*)(gA32);
  float4 afc1 = *(const float4*)(gA32 + 4);
  gload_lds16(gB0, &Bh0[ldsOff]);

  for (int p = 0; p < NP; ++p) {
    float4 afn0 = make_float4(0.f, 0.f, 0.f, 0.f);
    float4 afn1 = make_float4(0.f, 0.f, 0.f, 0.f);
    if (p + 1 < NP) {
      const int kn = ((p + 1) >> 1) * 64 + ((p + 1) & 1) * 32;
      afn0 = *(const float4*)(gA32 + kn);
      afn1 = *(const float4*)(gA32 + kn + 4);
      unsigned short* Bd = ((p + 1) & 1) ? Bh1 : Bh0;
      gload_lds16(gB0 + kn, &Bd[ldsOff]);
      // oldest three outstanding = {afc0, afc1, B(p)} in any issue order of
      // the newer trio {afn0, afn1, B(p+1)} -> vmcnt(3) retires exactly them
      asm volatile("s_waitcnt vmcnt(3)" ::: "memory");
    } else {
      asm volatile("s_waitcnt vmcnt(0)" ::: "memory");
    }
    // convert current A chunk -> Ah[p&1] (16B write, lane-linear)
    {
      unsigned int u0, u1, u2, u3;
      asm("v_cvt_pk_bf16_f32 %0, %1, %2" : "=v"(u0) : "v"(afc0.x), "v"(afc0.y));
      asm("v_cvt_pk_bf16_f32 %0, %1, %2" : "=v"(u1) : "v"(afc0.z), "v"(afc0.w));
      asm("v_cvt_pk_bf16_f32 %0, %1, %2" : "=v"(u2) : "v"(afc1.x), "v"(afc1.y));
      asm("v_cvt_pk_bf16_f32 %0, %1, %2" : "=v"(u3) : "v"(afc1.z), "v"(afc1.w));
      unsigned short* Ad = (p & 1) ? Ah1 : Ah0;
      uint4 pk; pk.x = u0; pk.y = u1; pk.z = u2; pk.w = u3;
      *(uint4*)&Ad[ldsOff] = pk;                // ds_write_b128
    }
    asm volatile("s_waitcnt lgkmcnt(0)" ::: "memory");  // write visible
    __builtin_amdgcn_s_barrier();          // all waves' A(p),B(p) in LDS
    __builtin_amdgcn_sched_barrier(0);
    const unsigned short* Asb = (p & 1) ? Ah1 : Ah0;
    const unsigned short* Bsb = (p & 1) ? Bh1 : Bh0;
    short8 af[2], bf[4];
#pragma unroll
    for (int i = 0; i < 2; i++) af[i] = *(const short8*)&Asb[aOff[i]];
#pragma unroll
    for (int j = 0; j < 4; j++) bf[j] = *(const short8*)&Bsb[bOff[j]];
#pragma unroll
    for (int i = 0; i < 2; i++)
#pragma unroll
      for (int j = 0; j < 4; j++)
        acc[i][j] = __builtin_amdgcn_mfma_f32_16x16x32_bf16(af[i], bf[j],
                                                            acc[i][j], 0, 0, 0);
    __builtin_amdgcn_sched_barrier(0);
    __builtin_amdgcn_s_barrier();          // reads done; next overwrite safe
    afc0 = afn0; afc1 = afn1;
  }

  // ---- epilogue: RoPE/transpose into LDS tile, then coalesced stores ----
  unsigned short (*Obuf)[136] = (unsigned short (*)[136])SH;

  const int region = n0 / kHidden;  // 0=Q 1=K 2=V (128-blocks don't straddle)
  const int b = m0 >> 11, s0 = m0 & 2047;
  const int h0 = (n0 % kHidden) >> 6;      // first of the 2 heads in this tile
  const int rowL0 = wm * 32 + kq * 4;      // local C row (s offset)

  if (region == 2) {
#pragma unroll
    for (int i = 0; i < 2; i++)
#pragma unroll
      for (int r = 0; r < 4; r++) {
        const int rowL = rowL0 + i * 16 + r;
#pragma unroll
        for (int j = 0; j < 4; j++)
          Obuf[wn * 64 + j * 16 + (lane & 15)][rowL] = f2bf(acc[i][j][r]);
      }
    __syncthreads();
#pragma unroll
    for (int it = 0; it < 4; it++) {
      const int t = tid + it * 512;       // 0..2047 16B chunks
      const int s8 = t & 15, rowc = t >> 4;
      const int hl = rowc >> 6, d = rowc & 63;
      *(short8*)(Vt + ((size_t)(b * kH + h0 + hl) * kD + d) * kS + s0 + s8 * 8) =
          *(const short8*)&Obuf[rowc][s8 * 8];
    }
  } else {
    unsigned short* dst = (region == 0) ? Qr : Kr;
    const float qscale = (region == 0) ? 0.125f : 1.f;
#pragma unroll
    for (int i = 0; i < 2; i++)
#pragma unroll
      for (int r = 0; r < 4; r++) {
        const int rowL = rowL0 + i * 16 + r;
        const int s = s0 + rowL;
        const float* cs = cosp + ((size_t)(b * kS + s)) * kD;
        const float* sns = sinp + ((size_t)(b * kS + s)) * kD;
#pragma unroll
        for (int jp = 0; jp < 2; jp++) {
          const int colL = wn * 64 + jp * 16 + (lane & 15);  // (colL&63) < 32
          const int d = colL & 63;
          const float c = cs[d], sn = sns[d];  // == cs[d+32], sns[d+32]
          const float xlo = acc[i][jp][r], xhi = acc[i][jp + 2][r];
          Obuf[rowL][colL]      = f2bf((xlo * c - xhi * sn) * qscale);
          Obuf[rowL][colL + 32] = f2bf((xhi * c + xlo * sn) * qscale);
        }
      }
    __syncthreads();
#pragma unroll
    for (int it = 0; it < 4; it++) {
      const int t = tid + it * 512;       // 0..2047 16B chunks
      const int d8 = t & 7, sl = (t >> 3) & 127, hl = t >> 10;
      *(short8*)(dst + ((size_t)(b * kH + h0 + hl) * kS + s0 + sl) * kD + d8 * 8) =
          *(const short8*)&Obuf[sl][hl * 64 + d8 * 8];
    }
  }
}

// ---------------------------------------------------------------------------
// GEMM2 (R13-exact): C fp32 = A @ B^T (bf16 in), 4 waves, 128x64 tile
// (768 blocks = 3/CU), simple 2-barrier K64 loop. Wave sub-tile 64x32.
// ---------------------------------------------------------------------------
__global__ __launch_bounds__(256) void gemm_bf16_nt(
    const unsigned short* __restrict__ A, const unsigned short* __restrict__ B,
    float* __restrict__ C, int M, int N, int K) {
  __shared__ unsigned short As[128 * 64];  // 16 KB
  __shared__ unsigned short Bs[64 * 64];   // 8 KB

  const int tid = threadIdx.x;
  const int lane = tid & 63;
  const int wave = tid >> 6;
  const int l15 = lane & 15;
  const int m0 = blockIdx.x * 128;
  const int n0 = blockIdx.y * 64;

  int ldsA[4];
  const unsigned short* gA[4];
#pragma unroll
  for (int t = 0; t < 4; t++) {
    const int ci = (wave * 4 + t) * 64 + lane;   // 0..1023
    const int row = ci >> 3;
    const int c = (ci & 7) ^ (row & 7);
    ldsA[t] = ci * 8;
    gA[t] = A + (size_t)(m0 + row) * K + c * 8;
  }
  int ldsB[2];
  const unsigned short* gB[2];
#pragma unroll
  for (int t = 0; t < 2; t++) {
    const int ci = (wave * 2 + t) * 64 + lane;   // 0..511
    const int row = ci >> 3;                     // 0..63
    const int c = (ci & 7) ^ (row & 7);
    ldsB[t] = ci * 8;
    gB[t] = B + (size_t)(n0 + row) * K + c * 8;
  }

  const int wm = wave >> 1, wn = wave & 1;
  const int mr = wm * 64 + l15;
  const int nr = wn * 32 + l15;
  const int kq = lane >> 4;

  floatx4 acc[4][2];
#pragma unroll
  for (int i = 0; i < 4; i++)
#pragma unroll
    for (int j = 0; j < 2; j++) acc[i][j] = (floatx4)(0.f);

  for (int k0 = 0; k0 < K; k0 += 64) {
    if (k0) __syncthreads();
#pragma unroll
    for (int t = 0; t < 4; t++) gload_lds16(gA[t] + k0, &As[ldsA[t]]);
#pragma unroll
    for (int t = 0; t < 2; t++) gload_lds16(gB[t] + k0, &Bs[ldsB[t]]);
    __syncthreads();
#pragma unroll
    for (int s = 0; s < 2; s++) {
      short8 af[4], bf[2];
#pragma unroll
      for (int i = 0; i < 4; i++)
        af[i] = *(const short8*)&As[(mr + i * 16) * 64 + (((s * 4 + kq) ^ ((mr + i * 16) & 7)) * 8)];
#pragma unroll
      for (int j = 0; j < 2; j++)
        bf[j] = *(const short8*)&Bs[(nr + j * 16) * 64 + (((s * 4 + kq) ^ ((nr + j * 16) & 7)) * 8)];
#pragma unroll
      for (int i = 0; i < 4; i++)
#pragma unroll
        for (int j = 0; j < 2; j++)
          acc[i][j] = __builtin_amdgcn_mfma_f32_16x16x32_bf16(af[i], bf[j],
                                                              acc[i][j], 0, 0, 0);
    }
  }

  const int crow = m0 + wm * 64 + kq * 4;
  const int ccol = n0 + wn * 32 + l15;
#pragma unroll
  for (int i = 0; i < 4; i++)
#pragma unroll
    for (int r = 0; r < 4; r++) {
      float* cp = C + (size_t)(crow + i * 16 + r) * N + ccol;
#pragma unroll
      for (int j = 0; j < 2; j++) cp[j * 16] = acc[i][j][r];
    }
}

// ---------------------------------------------------------------------------
// Attention v4 (R14-exact): AQT=64 queries, 192 keys per block, 4 waves =
// (tq, kh/dh). Each wave: 32 queries x 96 keys. QK^T MFMA (frags from
// global, clamped+masked) -> exp WITHOUT max-sub -> P bf16 in A-frag-native
// LDS -> PV MFMA with V^T B-frags from global. Out staged through LDS.
// ---------------------------------------------------------------------------
constexpr int AQT = 64;

__global__ __launch_bounds__(256) void attn_v4(
    const unsigned short* __restrict__ Qr, const unsigned short* __restrict__ Kr,
    const unsigned short* __restrict__ Vt, unsigned short* __restrict__ out) {
  __shared__ unsigned short Pfrag[4][6][64][8];  // 24.576 KB
  __shared__ float Ssum[2][AQT];

  const int tid = threadIdx.x;
  const int lane = tid & 63;
  const int wave = tid >> 6;
  const int quad = lane >> 4;
  const int l15 = lane & 15;
  const int qbase = blockIdx.x * AQT;
  const int h = blockIdx.y, b = blockIdx.z;
  const int bh = b * kH + h;
  const int kbase = qbase - 64;
  const int tq = wave >> 1;  // 0,1: query half (32 rows)
  const int kh = wave & 1;   // QK^T: key-half (96 keys). PV: d-half (32 cols).

  // ---- Q A-frags: 2 query sub-tiles x (lo,hi) ----
  short8 a0[2], a1[2];
#pragma unroll
  for (int qs = 0; qs < 2; qs++) {
    const unsigned short* qsrc =
        Qr + ((size_t)bh * kS + qbase + tq * 32 + qs * 16 + l15) * kD + quad * 8;
    a0[qs] = *(const short8*)qsrc;
    a1[qs] = *(const short8*)(qsrc + 32);
  }

  // ---- K B-frags (clamped) + QK^T MFMA: acc[qs][g] ----
  floatx4 acc[2][6];
  const unsigned short* ksrc = Kr + (size_t)bh * kS * kD;
#pragma unroll
  for (int g = 0; g < 6; g++) {
    int row = kbase + (kh * 6 + g) * 16 + l15;
    row = min(max(row, 0), kS - 1);
    const unsigned short* kp = ksrc + (size_t)row * kD + quad * 8;
    const short8 b0 = *(const short8*)kp;
    const short8 b1 = *(const short8*)(kp + 32);
#pragma unroll
    for (int qs = 0; qs < 2; qs++) {
      floatx4 z = (floatx4)(0.f);
      z = __builtin_amdgcn_mfma_f32_16x16x32_bf16(a0[qs], b0, z, 0, 0, 0);
      z = __builtin_amdgcn_mfma_f32_16x16x32_bf16(a1[qs], b1, z, 0, 0, 0);
      acc[qs][g] = z;
    }
  }

  // ---- V^T B-frags from global (issue while exp runs) ----
  short8 vf[2][6];
  {
    const unsigned short* vbase = Vt + (size_t)bh * kD * kS;
#pragma unroll
    for (int nt = 0; nt < 2; nt++) {
      const unsigned short* vrow = vbase + (size_t)(kh * 32 + nt * 16 + l15) * kS;
#pragma unroll
      for (int kk = 0; kk < 6; kk++) {
        int s0 = kbase + kk * 32 + quad * 8;
        s0 = min(max(s0, 0), kS - 8);  // chunk-aligned: garbage rows have P=0
        vf[nt][kk] = *(const short8*)(vrow + s0);
      }
    }
  }

  // ---- exp (no max-sub) + partial sums + P(bf16) into A-frag LDS ----
#pragma unroll
  for (int qs = 0; qs < 2; qs++) {
    const int qgrp = tq * 2 + qs;
#pragma unroll
    for (int r = 0; r < 4; r++) {
      const int q = tq * 32 + qs * 16 + quad * 4 + r;  // local query 0..63
      float s = 0.f;
#pragma unroll
      for (int g = 0; g < 6; g++) {
        const int key = (kh * 6 + g) * 16 + l15;       // 0..191
        const int kg_ = kbase + key;
        const bool valid = (key >= q) && (key <= q + 128) && (kg_ >= 0) && (kg_ < kS);
        const float e = valid ? __expf(acc[qs][g][r]) : 0.f;
        s += e;
        Pfrag[qgrp][key >> 5][((key >> 3) & 3) * 16 + quad * 4 + r][key & 7] = f2bf(e);
      }
#pragma unroll
      for (int off = 1; off < 16; off <<= 1) s += __shfl_xor(s, off, 64);
      if (l15 == 0) Ssum[kh][q] = s;
    }
  }
  __syncthreads();

  // ---- PV MFMA: A = Pfrag (contiguous-lane b128 reads), B = preloaded vf ----
  floatx4 o[2][2];  // [qs][nt]
#pragma unroll
  for (int qs = 0; qs < 2; qs++)
#pragma unroll
    for (int nt = 0; nt < 2; nt++) o[qs][nt] = (floatx4)(0.f);
#pragma unroll
  for (int kk = 0; kk < 6; kk++) {
#pragma unroll
    for (int qs = 0; qs < 2; qs++) {
      const short8 pa = *(const short8*)&Pfrag[tq * 2 + qs][kk][lane][0];
      o[qs][0] = __builtin_amdgcn_mfma_f32_16x16x32_bf16(pa, vf[0][kk], o[qs][0], 0, 0, 0);
      o[qs][1] = __builtin_amdgcn_mfma_f32_16x16x32_bf16(pa, vf[1][kk], o[qs][1], 0, 0, 0);
    }
  }

  // ---- epilogue: normalize into LDS out-tile, then 16B coalesced stores ----
  __syncthreads();  // all waves done reading Pfrag; reuse as Ob
  unsigned short (*Ob)[68] = (unsigned short (*)[68])Pfrag;  // [64][68] pad
#pragma unroll
  for (int qs = 0; qs < 2; qs++)
#pragma unroll
    for (int r = 0; r < 4; r++) {
      const int q = tq * 32 + qs * 16 + quad * 4 + r;
      const float inv = 1.f / (Ssum[0][q] + Ssum[1][q]);
      Ob[q][kh * 32 + l15] = f2bf(o[qs][0][r] * inv);
      Ob[q][kh * 32 + 16 + l15] = f2bf(o[qs][1][r] * inv);
    }
  __syncthreads();
#pragma unroll
  for (int it = 0; it < 2; it++) {
    const int t = tid + it * 256;          // 0..511: 64 rows x 8 chunks
    const int q = t >> 3, d8 = t & 7;
    *(short8*)(out + ((size_t)(b * kS + qbase + q)) * kHidden + h * kD + d8 * 8) =
        *(const short8*)&Ob[q][d8 * 8];
  }
}

// ---------------------------------------------------------------------------
extern "C" void kernel_launch(void* const* d_in, const int* in_sizes, int n_in,
                              void* d_out, int out_size, void* d_ws,
                              size_t ws_size, hipStream_t stream) {
  const float* hidden = (const float*)d_in[0];
  const float* cosp = (const float*)d_in[1];
  const float* sinp = (const float*)d_in[2];
  // d_in[3]: attention_mask — deterministic sliding-window mask, not read.
  const float* wqkv = (const float*)d_in[4];
  const float* wo = (const float*)d_in[5];
  float* out = (float*)d_out;

  const int M = kB * kS;  // 8192
  const size_t szH = (size_t)M * kHidden;

  unsigned short* hbf = (unsigned short*)d_ws;   // unused (kept for layout)
  unsigned short* wqkvbf = hbf + szH;
  unsigned short* wobf = wqkvbf + (size_t)kQKV * kHidden;
  unsigned short* attnbf = wobf + (size_t)kHidden * kHidden;
  unsigned short* Qrb = attnbf + szH;
  unsigned short* Krb = Qrb + szH;
  unsigned short* Vtb = Krb + szH;

  const int ncvt = (kQKV * kHidden + kHidden * kHidden) / 4;  // 589824
  cvt_wts<<<(ncvt + 255) / 256, 256, 0, stream>>>(wqkv, wo, wqkvbf, wobf);

  dim3 g1(M / 128, kQKV / 128);
  gemm_qkv<<<g1, 512, 0, stream>>>(hidden, wqkvbf, cosp, sinp, Qrb, Krb, Vtb);

  dim3 ga(kS / AQT, kH, kB);
  attn_v4<<<ga, 256, 0, stream>>>(Qrb, Krb, Vtb, attnbf);

  dim3 g2(M / 128, kHidden / 64);
  gemm_bf16_nt<<<g2, 256, 0, stream>>>(attnbf, wobf, out, M, kHidden, kHidden);
}

// Round 12
// 206.534 us; speedup vs baseline: 1.0916x; 1.0916x over previous
//
#include <hip/hip_runtime.h>
#include <math.h>

// ModernBERT sliding-window attention.
// B=4 S=2048 H=12 D=64 HIDDEN=768 WINDOW=64 (|i-j|<=64 allowed).
// R19: consolidation to the measured optimum (R14 config, 206.1us).
// qkv = R12-exact 8-wave ping-pong (46.2us; 6 structural variants all lost:
// dbuf/4-wave/256-tile/A-direct/fused-cvt/8-wave-acc24).
// attn = v4 AQT=64 (R14 win, keys/query 5->3). nt = R13 128x64 (3 blocks/CU;
// ping-pong there regressed +3.7us). cvt_all full (fused variant refuted).
// Pipeline: [cvt_all->bf16] -> [GEMM qkv + RoPE/transpose epilogue] ->
//           [MFMA attn] -> [GEMM out].

typedef __attribute__((ext_vector_type(8))) short short8;
typedef __attribute__((ext_vector_type(4))) float floatx4;

constexpr int kB = 4;
constexpr int kS = 2048;
constexpr int kH = 12;
constexpr int kD = 64;
constexpr int kHidden = 768;
constexpr int kQKV = 3 * kHidden;  // 2304

__device__ __forceinline__ unsigned short f2bf(float f) {
  union { float f; unsigned int u; } x; x.f = f;
  unsigned int r = (x.u + 0x7fffu + ((x.u >> 16) & 1u)) >> 16;  // RNE
  return (unsigned short)r;
}

// one kernel converts hidden, Wqkv, Wo (independent elementwise ranges)
__global__ __launch_bounds__(256) void cvt_all(
    const float* __restrict__ h, const float* __restrict__ wqkv,
    const float* __restrict__ wo, unsigned short* __restrict__ hb,
    unsigned short* __restrict__ wqb, unsigned short* __restrict__ wob) {
  constexpr int n1 = kB * kS * kHidden / 4;      // 1572864
  constexpr int n2 = kQKV * kHidden / 4;         // 442368
  constexpr int n3 = kHidden * kHidden / 4;      // 147456
  int i = blockIdx.x * 256 + threadIdx.x;
  const float* src;
  unsigned short* dst;
  if (i < n1) {
    src = h; dst = hb;
  } else if (i < n1 + n2) {
    i -= n1; src = wqkv; dst = wqb;
  } else {
    i -= n1 + n2; if (i >= n3) return; src = wo; dst = wob;
  }
  const float4 v = ((const float4*)src)[i];
  ushort4 o;
  o.x = f2bf(v.x); o.y = f2bf(v.y); o.z = f2bf(v.z); o.w = f2bf(v.w);
  ((ushort4*)dst)[i] = o;
}

__device__ __forceinline__ void gload_lds16(const unsigned short* g, unsigned short* l) {
  __builtin_amdgcn_global_load_lds(
      (const __attribute__((address_space(1))) unsigned int*)g,
      (__attribute__((address_space(3))) unsigned int*)l, 16, 0, 0);
}

// ---------------------------------------------------------------------------
// GEMM1 (R12-exact): qkv = hidden @ Wqkv^T with fused RoPE epilogue.
// cols<768 -> Qr (RoPE, *0.125, bf16 [b,h,s,d]); [768,1536) -> Kr (RoPE, bf16
// [b,h,s,d]); >=1536 -> Vt (bf16 TRANSPOSED [b,h,d,s]).
// 8 waves, 128x128 tile, ping-pong half-K pipeline (24 phases, 2 loads/wave
// per phase, steady-state s_waitcnt vmcnt(2)).
// ---------------------------------------------------------------------------
__global__ __launch_bounds__(512) void gemm_qkv(
    const unsigned short* __restrict__ A,   // [M][768] bf16 hidden
    const unsigned short* __restrict__ B,   // [2304][768] bf16 Wqkv
    const float* __restrict__ cosp, const float* __restrict__ sinp,
    unsigned short* __restrict__ Qr, unsigned short* __restrict__ Kr,
    unsigned short* __restrict__ Vt) {
  constexpr int K = kHidden;
  constexpr int NP = 2 * (K / 64);          // 24 phases
  __shared__ unsigned short SH[128 * 136];  // 34816 B -> 4 blocks/CU
  unsigned short* Ah0 = SH;                 // 128x32 bf16 (8 KB)
  unsigned short* Ah1 = SH + 4096;
  unsigned short* Bh0 = SH + 8192;
  unsigned short* Bh1 = SH + 12288;

  const int tid = threadIdx.x;    // 0..511
  const int lane = tid & 63;
  const int wave = tid >> 6;      // 0..7
  const int m0 = blockIdx.x * 128;
  const int n0 = blockIdx.y * 128;

  const int sc = wave * 64 + lane;        // 0..511
  const int srow = sc >> 2;               // 0..127
  const int sgc = ((sc & 3) ^ ((srow >> 1) & 3)) * 8;  // elem offset in half
  const int ldsOff = sc * 8;              // shorts
  const unsigned short* gA0 = A + (size_t)(m0 + srow) * K + sgc;  // half 0
  const unsigned short* gB0 = B + (size_t)(n0 + srow) * K + sgc;

  const int wm = wave >> 1, wn = wave & 1;   // 4 row-groups x 2 col-groups
  const int mr = wm * 32 + (lane & 15);
  const int nr = wn * 64 + (lane & 15);
  const int kq = lane >> 4;

  int aOff[2], bOff[4];
#pragma unroll
  for (int i = 0; i < 2; i++) {
    const int r = mr + i * 16;
    aOff[i] = (r * 4 + (kq ^ ((r >> 1) & 3))) * 8;
  }
#pragma unroll
  for (int j = 0; j < 4; j++) {
    const int r = nr + j * 16;
    bOff[j] = (r * 4 + (kq ^ ((r >> 1) & 3))) * 8;
  }

  floatx4 acc[2][4];
#pragma unroll
  for (int i = 0; i < 2; i++)
#pragma unroll
    for (int j = 0; j < 4; j++) acc[i][j] = (floatx4)(0.f);

  // prologue: stage phase-0 data (half 0 of k0=0)
  gload_lds16(gA0, &Ah0[ldsOff]);
  gload_lds16(gB0, &Bh0[ldsOff]);

  for (int p = 0; p < NP; ++p) {
    if (p + 1 < NP) {
      const int kn = ((p + 1) >> 1) * 64 + ((p + 1) & 1) * 32;
      unsigned short* Ad = ((p + 1) & 1) ? Ah1 : Ah0;
      unsigned short* Bd = ((p + 1) & 1) ? Bh1 : Bh0;
      gload_lds16(gA0 + kn, &Ad[ldsOff]);
      gload_lds16(gB0 + kn, &Bd[ldsOff]);
      asm volatile("s_waitcnt vmcnt(2)" ::: "memory");
    } else {
      asm volatile("s_waitcnt vmcnt(0)" ::: "memory");
    }
    __builtin_amdgcn_s_barrier();          // all waves' current half landed
    __builtin_amdgcn_sched_barrier(0);
    const unsigned short* Asb = (p & 1) ? Ah1 : Ah0;
    const unsigned short* Bsb = (p & 1) ? Bh1 : Bh0;
    short8 af[2], bf[4];
#pragma unroll
    for (int i = 0; i < 2; i++) af[i] = *(const short8*)&Asb[aOff[i]];
#pragma unroll
    for (int j = 0; j < 4; j++) bf[j] = *(const short8*)&Bsb[bOff[j]];
#pragma unroll
    for (int i = 0; i < 2; i++)
#pragma unroll
      for (int j = 0; j < 4; j++)
        acc[i][j] = __builtin_amdgcn_mfma_f32_16x16x32_bf16(af[i], bf[j],
                                                            acc[i][j], 0, 0, 0);
    __builtin_amdgcn_sched_barrier(0);
    __builtin_amdgcn_s_barrier();          // reads done; next overwrite safe
  }

  // ---- epilogue: RoPE/transpose into LDS tile, then coalesced stores ----
  unsigned short (*Obuf)[136] = (unsigned short (*)[136])SH;

  const int region = n0 / kHidden;  // 0=Q 1=K 2=V (128-blocks don't straddle)
  const int b = m0 >> 11, s0 = m0 & 2047;
  const int h0 = (n0 % kHidden) >> 6;      // first of the 2 heads in this tile
  const int rowL0 = wm * 32 + kq * 4;      // local C row (s offset)

  if (region == 2) {
#pragma unroll
    for (int i = 0; i < 2; i++)
#pragma unroll
      for (int r = 0; r < 4; r++) {
        const int rowL = rowL0 + i * 16 + r;
#pragma unroll
        for (int j = 0; j < 4; j++)
          Obuf[wn * 64 + j * 16 + (lane & 15)][rowL] = f2bf(acc[i][j][r]);
      }
    __syncthreads();
#pragma unroll
    for (int it = 0; it < 4; it++) {
      const int t = tid + it * 512;       // 0..2047 16B chunks
      const int s8 = t & 15, rowc = t >> 4;
      const int hl = rowc >> 6, d = rowc & 63;
      *(short8*)(Vt + ((size_t)(b * kH + h0 + hl) * kD + d) * kS + s0 + s8 * 8) =
          *(const short8*)&Obuf[rowc][s8 * 8];
    }
  } else {
    unsigned short* dst = (region == 0) ? Qr : Kr;
    const float qscale = (region == 0) ? 0.125f : 1.f;
#pragma unroll
    for (int i = 0; i < 2; i++)
#pragma unroll
      for (int r = 0; r < 4; r++) {
        const int rowL = rowL0 + i * 16 + r;
        const int s = s0 + rowL;
        const float* cs = cosp + ((size_t)(b * kS + s)) * kD;
        const float* sns = sinp + ((size_t)(b * kS + s)) * kD;
#pragma unroll
        for (int jp = 0; jp < 2; jp++) {
          const int colL = wn * 64 + jp * 16 + (lane & 15);  // (colL&63) < 32
          const int d = colL & 63;
          const float c = cs[d], sn = sns[d];  // == cs[d+32], sns[d+32]
          const float xlo = acc[i][jp][r], xhi = acc[i][jp + 2][r];
          Obuf[rowL][colL]      = f2bf((xlo * c - xhi * sn) * qscale);
          Obuf[rowL][colL + 32] = f2bf((xhi * c + xlo * sn) * qscale);
        }
      }
    __syncthreads();
#pragma unroll
    for (int it = 0; it < 4; it++) {
      const int t = tid + it * 512;       // 0..2047 16B chunks
      const int d8 = t & 7, sl = (t >> 3) & 127, hl = t >> 10;
      *(short8*)(dst + ((size_t)(b * kH + h0 + hl) * kS + s0 + sl) * kD + d8 * 8) =
          *(const short8*)&Obuf[sl][hl * 64 + d8 * 8];
    }
  }
}

// ---------------------------------------------------------------------------
// GEMM2 (R13-exact): C fp32 = A @ B^T (bf16 in), 4 waves, 128x64 tile
// (768 blocks = 3/CU), simple 2-barrier K64 loop. Wave sub-tile 64x32.
// ---------------------------------------------------------------------------
__global__ __launch_bounds__(256) void gemm_bf16_nt(
    const unsigned short* __restrict__ A, const unsigned short* __restrict__ B,
    float* __restrict__ C, int M, int N, int K) {
  __shared__ unsigned short As[128 * 64];  // 16 KB
  __shared__ unsigned short Bs[64 * 64];   // 8 KB

  const int tid = threadIdx.x;
  const int lane = tid & 63;
  const int wave = tid >> 6;
  const int l15 = lane & 15;
  const int m0 = blockIdx.x * 128;
  const int n0 = blockIdx.y * 64;

  int ldsA[4];
  const unsigned short* gA[4];
#pragma unroll
  for (int t = 0; t < 4; t++) {
    const int ci = (wave * 4 + t) * 64 + lane;   // 0..1023
    const int row = ci >> 3;
    const int c = (ci & 7) ^ (row & 7);
    ldsA[t] = ci * 8;
    gA[t] = A + (size_t)(m0 + row) * K + c * 8;
  }
  int ldsB[2];
  const unsigned short* gB[2];
#pragma unroll
  for (int t = 0; t < 2; t++) {
    const int ci = (wave * 2 + t) * 64 + lane;   // 0..511
    const int row = ci >> 3;                     // 0..63
    const int c = (ci & 7) ^ (row & 7);
    ldsB[t] = ci * 8;
    gB[t] = B + (size_t)(n0 + row) * K + c * 8;
  }

  const int wm = wave >> 1, wn = wave & 1;
  const int mr = wm * 64 + l15;
  const int nr = wn * 32 + l15;
  const int kq = lane >> 4;

  floatx4 acc[4][2];
#pragma unroll
  for (int i = 0; i < 4; i++)
#pragma unroll
    for (int j = 0; j < 2; j++) acc[i][j] = (floatx4)(0.f);

  for (int k0 = 0; k0 < K; k0 += 64) {
    if (k0) __syncthreads();
#pragma unroll
    for (int t = 0; t < 4; t++) gload_lds16(gA[t] + k0, &As[ldsA[t]]);
#pragma unroll
    for (int t = 0; t < 2; t++) gload_lds16(gB[t] + k0, &Bs[ldsB[t]]);
    __syncthreads();
#pragma unroll
    for (int s = 0; s < 2; s++) {
      short8 af[4], bf[2];
#pragma unroll
      for (int i = 0; i < 4; i++)
        af[i] = *(const short8*)&As[(mr + i * 16) * 64 + (((s * 4 + kq) ^ ((mr + i * 16) & 7)) * 8)];
#pragma unroll
      for (int j = 0; j < 2; j++)
        bf[j] = *(const short8*)&Bs[(nr + j * 16) * 64 + (((s * 4 + kq) ^ ((nr + j * 16) & 7)) * 8)];
#pragma unroll
      for (int i = 0; i < 4; i++)
#pragma unroll
        for (int j = 0; j < 2; j++)
          acc[i][j] = __builtin_amdgcn_mfma_f32_16x16x32_bf16(af[i], bf[j],
                                                              acc[i][j], 0, 0, 0);
    }
  }

  const int crow = m0 + wm * 64 + kq * 4;
  const int ccol = n0 + wn * 32 + l15;
#pragma unroll
  for (int i = 0; i < 4; i++)
#pragma unroll
    for (int r = 0; r < 4; r++) {
      float* cp = C + (size_t)(crow + i * 16 + r) * N + ccol;
#pragma unroll
      for (int j = 0; j < 2; j++) cp[j * 16] = acc[i][j][r];
    }
}

// ---------------------------------------------------------------------------
// Attention v4 (R14-exact): AQT=64 queries, 192 keys per block, 4 waves =
// (tq, kh/dh). Each wave: 32 queries x 96 keys. QK^T MFMA (frags from
// global, clamped+masked) -> exp WITHOUT max-sub -> P bf16 in A-frag-native
// LDS -> PV MFMA with V^T B-frags from global. Out staged through LDS.
// ---------------------------------------------------------------------------
constexpr int AQT = 64;

__global__ __launch_bounds__(256) void attn_v4(
    const unsigned short* __restrict__ Qr, const unsigned short* __restrict__ Kr,
    const unsigned short* __restrict__ Vt, unsigned short* __restrict__ out) {
  __shared__ unsigned short Pfrag[4][6][64][8];  // 24.576 KB
  __shared__ float Ssum[2][AQT];

  const int tid = threadIdx.x;
  const int lane = tid & 63;
  const int wave = tid >> 6;
  const int quad = lane >> 4;
  const int l15 = lane & 15;
  const int qbase = blockIdx.x * AQT;
  const int h = blockIdx.y, b = blockIdx.z;
  const int bh = b * kH + h;
  const int kbase = qbase - 64;
  const int tq = wave >> 1;  // 0,1: query half (32 rows)
  const int kh = wave & 1;   // QK^T: key-half (96 keys). PV: d-half (32 cols).

  // ---- Q A-frags: 2 query sub-tiles x (lo,hi) ----
  short8 a0[2], a1[2];
#pragma unroll
  for (int qs = 0; qs < 2; qs++) {
    const unsigned short* qsrc =
        Qr + ((size_t)bh * kS + qbase + tq * 32 + qs * 16 + l15) * kD + quad * 8;
    a0[qs] = *(const short8*)qsrc;
    a1[qs] = *(const short8*)(qsrc + 32);
  }

  // ---- K B-frags (clamped) + QK^T MFMA: acc[qs][g] ----
  floatx4 acc[2][6];
  const unsigned short* ksrc = Kr + (size_t)bh * kS * kD;
#pragma unroll
  for (int g = 0; g < 6; g++) {
    int row = kbase + (kh * 6 + g) * 16 + l15;
    row = min(max(row, 0), kS - 1);
    const unsigned short* kp = ksrc + (size_t)row * kD + quad * 8;
    const short8 b0 = *(const short8*)kp;
    const short8 b1 = *(const short8*)(kp + 32);
#pragma unroll
    for (int qs = 0; qs < 2; qs++) {
      floatx4 z = (floatx4)(0.f);
      z = __builtin_amdgcn_mfma_f32_16x16x32_bf16(a0[qs], b0, z, 0, 0, 0);
      z = __builtin_amdgcn_mfma_f32_16x16x32_bf16(a1[qs], b1, z, 0, 0, 0);
      acc[qs][g] = z;
    }
  }

  // ---- V^T B-frags from global (issue while exp runs) ----
  short8 vf[2][6];
  {
    const unsigned short* vbase = Vt + (size_t)bh * kD * kS;
#pragma unroll
    for (int nt = 0; nt < 2; nt++) {
      const unsigned short* vrow = vbase + (size_t)(kh * 32 + nt * 16 + l15) * kS;
#pragma unroll
      for (int kk = 0; kk < 6; kk++) {
        int s0 = kbase + kk * 32 + quad * 8;
        s0 = min(max(s0, 0), kS - 8);  // chunk-aligned: garbage rows have P=0
        vf[nt][kk] = *(const short8*)(vrow + s0);
      }
    }
  }

  // ---- exp (no max-sub) + partial sums + P(bf16) into A-frag LDS ----
#pragma unroll
  for (int qs = 0; qs < 2; qs++) {
    const int qgrp = tq * 2 + qs;
#pragma unroll
    for (int r = 0; r < 4; r++) {
      const int q = tq * 32 + qs * 16 + quad * 4 + r;  // local query 0..63
      float s = 0.f;
#pragma unroll
      for (int g = 0; g < 6; g++) {
        const int key = (kh * 6 + g) * 16 + l15;       // 0..191
        const int kg_ = kbase + key;
        const bool valid = (key >= q) && (key <= q + 128) && (kg_ >= 0) && (kg_ < kS);
        const float e = valid ? __expf(acc[qs][g][r]) : 0.f;
        s += e;
        Pfrag[qgrp][key >> 5][((key >> 3) & 3) * 16 + quad * 4 + r][key & 7] = f2bf(e);
      }
#pragma unroll
      for (int off = 1; off < 16; off <<= 1) s += __shfl_xor(s, off, 64);
      if (l15 == 0) Ssum[kh][q] = s;
    }
  }
  __syncthreads();

  // ---- PV MFMA: A = Pfrag (contiguous-lane b128 reads), B = preloaded vf ----
  floatx4 o[2][2];  // [qs][nt]
#pragma unroll
  for (int qs = 0; qs < 2; qs++)
#pragma unroll
    for (int nt = 0; nt < 2; nt++) o[qs][nt] = (floatx4)(0.f);
#pragma unroll
  for (int kk = 0; kk < 6; kk++) {
#pragma unroll
    for (int qs = 0; qs < 2; qs++) {
      const short8 pa = *(const short8*)&Pfrag[tq * 2 + qs][kk][lane][0];
      o[qs][0] = __builtin_amdgcn_mfma_f32_16x16x32_bf16(pa, vf[0][kk], o[qs][0], 0, 0, 0);
      o[qs][1] = __builtin_amdgcn_mfma_f32_16x16x32_bf16(pa, vf[1][kk], o[qs][1], 0, 0, 0);
    }
  }

  // ---- epilogue: normalize into LDS out-tile, then 16B coalesced stores ----
  __syncthreads();  // all waves done reading Pfrag; reuse as Ob
  unsigned short (*Ob)[68] = (unsigned short (*)[68])Pfrag;  // [64][68] pad
#pragma unroll
  for (int qs = 0; qs < 2; qs++)
#pragma unroll
    for (int r = 0; r < 4; r++) {
      const int q = tq * 32 + qs * 16 + quad * 4 + r;
      const float inv = 1.f / (Ssum[0][q] + Ssum[1][q]);
      Ob[q][kh * 32 + l15] = f2bf(o[qs][0][r] * inv);
      Ob[q][kh * 32 + 16 + l15] = f2bf(o[qs][1][r] * inv);
    }
  __syncthreads();
#pragma unroll
  for (int it = 0; it < 2; it++) {
    const int t = tid + it * 256;          // 0..511: 64 rows x 8 chunks
    const int q = t >> 3, d8 = t & 7;
    *(short8*)(out + ((size_t)(b * kS + qbase + q)) * kHidden + h * kD + d8 * 8) =
        *(const short8*)&Ob[q][d8 * 8];
  }
}

// ---------------------------------------------------------------------------
extern "C" void kernel_launch(void* const* d_in, const int* in_sizes, int n_in,
                              void* d_out, int out_size, void* d_ws,
                              size_t ws_size, hipStream_t stream) {
  const float* hidden = (const float*)d_in[0];
  const float* cosp = (const float*)d_in[1];
  const float* sinp = (const float*)d_in[2];
  // d_in[3]: attention_mask — deterministic sliding-window mask, not read.
  const float* wqkv = (const float*)d_in[4];
  const float* wo = (const float*)d_in[5];
  float* out = (float*)d_out;

  const int M = kB * kS;  // 8192
  const size_t szH = (size_t)M * kHidden;

  unsigned short* hbf = (unsigned short*)d_ws;
  unsigned short* wqkvbf = hbf + szH;
  unsigned short* wobf = wqkvbf + (size_t)kQKV * kHidden;
  unsigned short* attnbf = wobf + (size_t)kHidden * kHidden;
  unsigned short* Qrb = attnbf + szH;
  unsigned short* Krb = Qrb + szH;
  unsigned short* Vtb = Krb + szH;

  const int ncvt = (M * kHidden + kQKV * kHidden + kHidden * kHidden) / 4;
  cvt_all<<<(ncvt + 255) / 256, 256, 0, stream>>>(hidden, wqkv, wo, hbf,
                                                  wqkvbf, wobf);

  dim3 g1(M / 128, kQKV / 128);
  gemm_qkv<<<g1, 512, 0, stream>>>(hbf, wqkvbf, cosp, sinp, Qrb, Krb, Vtb);

  dim3 ga(kS / AQT, kH, kB);
  attn_v4<<<ga, 256, 0, stream>>>(Qrb, Krb, Vtb, attnbf);

  dim3 g2(M / 128, kHidden / 64);
  gemm_bf16_nt<<<g2, 256, 0, stream>>>(attnbf, wobf, out, M, kHidden, kHidden);
}

// Round 13
// 205.973 us; speedup vs baseline: 1.0945x; 1.0027x over previous
//
#include <hip/hip_runtime.h>
#include <math.h>

// ModernBERT sliding-window attention.
// B=4 S=2048 H=12 D=64 HIDDEN=768 WINDOW=64 (|i-j|<=64 allowed).
// R20: attn_v5 = swapped-QK^T softmax (T12): mfma(K,Q) makes keys lane-local
// -> P stored as [qgrp][query][key] tile with ONE b64 store per (qs,g)
// (was 48 scalar u16 scatter) and 4 shfl_xor total (was 32); PV A-frags
// read as 2x b64 from the plain tile. LDS 25.6KB (same 6 blocks/CU).
// qkv = R12-exact ping-pong (46.2us), nt = R13-exact 128x64, cvt_all full.
// Pipeline: [cvt_all->bf16] -> [GEMM qkv + RoPE/transpose epilogue] ->
//           [MFMA attn] -> [GEMM out].

typedef __attribute__((ext_vector_type(8))) short short8;
typedef __attribute__((ext_vector_type(4))) short short4v;
typedef __attribute__((ext_vector_type(4))) float floatx4;

constexpr int kB = 4;
constexpr int kS = 2048;
constexpr int kH = 12;
constexpr int kD = 64;
constexpr int kHidden = 768;
constexpr int kQKV = 3 * kHidden;  // 2304

__device__ __forceinline__ unsigned short f2bf(float f) {
  union { float f; unsigned int u; } x; x.f = f;
  unsigned int r = (x.u + 0x7fffu + ((x.u >> 16) & 1u)) >> 16;  // RNE
  return (unsigned short)r;
}

// one kernel converts hidden, Wqkv, Wo (independent elementwise ranges)
__global__ __launch_bounds__(256) void cvt_all(
    const float* __restrict__ h, const float* __restrict__ wqkv,
    const float* __restrict__ wo, unsigned short* __restrict__ hb,
    unsigned short* __restrict__ wqb, unsigned short* __restrict__ wob) {
  constexpr int n1 = kB * kS * kHidden / 4;      // 1572864
  constexpr int n2 = kQKV * kHidden / 4;         // 442368
  constexpr int n3 = kHidden * kHidden / 4;      // 147456
  int i = blockIdx.x * 256 + threadIdx.x;
  const float* src;
  unsigned short* dst;
  if (i < n1) {
    src = h; dst = hb;
  } else if (i < n1 + n2) {
    i -= n1; src = wqkv; dst = wqb;
  } else {
    i -= n1 + n2; if (i >= n3) return; src = wo; dst = wob;
  }
  const float4 v = ((const float4*)src)[i];
  ushort4 o;
  o.x = f2bf(v.x); o.y = f2bf(v.y); o.z = f2bf(v.z); o.w = f2bf(v.w);
  ((ushort4*)dst)[i] = o;
}

__device__ __forceinline__ void gload_lds16(const unsigned short* g, unsigned short* l) {
  __builtin_amdgcn_global_load_lds(
      (const __attribute__((address_space(1))) unsigned int*)g,
      (__attribute__((address_space(3))) unsigned int*)l, 16, 0, 0);
}

// ---------------------------------------------------------------------------
// GEMM1 (R12-exact): qkv = hidden @ Wqkv^T with fused RoPE epilogue.
// 8 waves, 128x128 tile, ping-pong half-K pipeline (24 phases, 2 loads/wave
// per phase, steady-state s_waitcnt vmcnt(2)).
// ---------------------------------------------------------------------------
__global__ __launch_bounds__(512) void gemm_qkv(
    const unsigned short* __restrict__ A,   // [M][768] bf16 hidden
    const unsigned short* __restrict__ B,   // [2304][768] bf16 Wqkv
    const float* __restrict__ cosp, const float* __restrict__ sinp,
    unsigned short* __restrict__ Qr, unsigned short* __restrict__ Kr,
    unsigned short* __restrict__ Vt) {
  constexpr int K = kHidden;
  constexpr int NP = 2 * (K / 64);          // 24 phases
  __shared__ unsigned short SH[128 * 136];  // 34816 B -> 4 blocks/CU
  unsigned short* Ah0 = SH;                 // 128x32 bf16 (8 KB)
  unsigned short* Ah1 = SH + 4096;
  unsigned short* Bh0 = SH + 8192;
  unsigned short* Bh1 = SH + 12288;

  const int tid = threadIdx.x;    // 0..511
  const int lane = tid & 63;
  const int wave = tid >> 6;      // 0..7
  const int m0 = blockIdx.x * 128;
  const int n0 = blockIdx.y * 128;

  const int sc = wave * 64 + lane;        // 0..511
  const int srow = sc >> 2;               // 0..127
  const int sgc = ((sc & 3) ^ ((srow >> 1) & 3)) * 8;  // elem offset in half
  const int ldsOff = sc * 8;              // shorts
  const unsigned short* gA0 = A + (size_t)(m0 + srow) * K + sgc;  // half 0
  const unsigned short* gB0 = B + (size_t)(n0 + srow) * K + sgc;

  const int wm = wave >> 1, wn = wave & 1;   // 4 row-groups x 2 col-groups
  const int mr = wm * 32 + (lane & 15);
  const int nr = wn * 64 + (lane & 15);
  const int kq = lane >> 4;

  int aOff[2], bOff[4];
#pragma unroll
  for (int i = 0; i < 2; i++) {
    const int r = mr + i * 16;
    aOff[i] = (r * 4 + (kq ^ ((r >> 1) & 3))) * 8;
  }
#pragma unroll
  for (int j = 0; j < 4; j++) {
    const int r = nr + j * 16;
    bOff[j] = (r * 4 + (kq ^ ((r >> 1) & 3))) * 8;
  }

  floatx4 acc[2][4];
#pragma unroll
  for (int i = 0; i < 2; i++)
#pragma unroll
    for (int j = 0; j < 4; j++) acc[i][j] = (floatx4)(0.f);

  // prologue: stage phase-0 data (half 0 of k0=0)
  gload_lds16(gA0, &Ah0[ldsOff]);
  gload_lds16(gB0, &Bh0[ldsOff]);

  for (int p = 0; p < NP; ++p) {
    if (p + 1 < NP) {
      const int kn = ((p + 1) >> 1) * 64 + ((p + 1) & 1) * 32;
      unsigned short* Ad = ((p + 1) & 1) ? Ah1 : Ah0;
      unsigned short* Bd = ((p + 1) & 1) ? Bh1 : Bh0;
      gload_lds16(gA0 + kn, &Ad[ldsOff]);
      gload_lds16(gB0 + kn, &Bd[ldsOff]);
      asm volatile("s_waitcnt vmcnt(2)" ::: "memory");
    } else {
      asm volatile("s_waitcnt vmcnt(0)" ::: "memory");
    }
    __builtin_amdgcn_s_barrier();          // all waves' current half landed
    __builtin_amdgcn_sched_barrier(0);
    const unsigned short* Asb = (p & 1) ? Ah1 : Ah0;
    const unsigned short* Bsb = (p & 1) ? Bh1 : Bh0;
    short8 af[2], bf[4];
#pragma unroll
    for (int i = 0; i < 2; i++) af[i] = *(const short8*)&Asb[aOff[i]];
#pragma unroll
    for (int j = 0; j < 4; j++) bf[j] = *(const short8*)&Bsb[bOff[j]];
#pragma unroll
    for (int i = 0; i < 2; i++)
#pragma unroll
      for (int j = 0; j < 4; j++)
        acc[i][j] = __builtin_amdgcn_mfma_f32_16x16x32_bf16(af[i], bf[j],
                                                            acc[i][j], 0, 0, 0);
    __builtin_amdgcn_sched_barrier(0);
    __builtin_amdgcn_s_barrier();          // reads done; next overwrite safe
  }

  // ---- epilogue: RoPE/transpose into LDS tile, then coalesced stores ----
  unsigned short (*Obuf)[136] = (unsigned short (*)[136])SH;

  const int region = n0 / kHidden;  // 0=Q 1=K 2=V (128-blocks don't straddle)
  const int b = m0 >> 11, s0 = m0 & 2047;
  const int h0 = (n0 % kHidden) >> 6;      // first of the 2 heads in this tile
  const int rowL0 = wm * 32 + kq * 4;      // local C row (s offset)

  if (region == 2) {
#pragma unroll
    for (int i = 0; i < 2; i++)
#pragma unroll
      for (int r = 0; r < 4; r++) {
        const int rowL = rowL0 + i * 16 + r;
#pragma unroll
        for (int j = 0; j < 4; j++)
          Obuf[wn * 64 + j * 16 + (lane & 15)][rowL] = f2bf(acc[i][j][r]);
      }
    __syncthreads();
#pragma unroll
    for (int it = 0; it < 4; it++) {
      const int t = tid + it * 512;       // 0..2047 16B chunks
      const int s8 = t & 15, rowc = t >> 4;
      const int hl = rowc >> 6, d = rowc & 63;
      *(short8*)(Vt + ((size_t)(b * kH + h0 + hl) * kD + d) * kS + s0 + s8 * 8) =
          *(const short8*)&Obuf[rowc][s8 * 8];
    }
  } else {
    unsigned short* dst = (region == 0) ? Qr : Kr;
    const float qscale = (region == 0) ? 0.125f : 1.f;
#pragma unroll
    for (int i = 0; i < 2; i++)
#pragma unroll
      for (int r = 0; r < 4; r++) {
        const int rowL = rowL0 + i * 16 + r;
        const int s = s0 + rowL;
        const float* cs = cosp + ((size_t)(b * kS + s)) * kD;
        const float* sns = sinp + ((size_t)(b * kS + s)) * kD;
#pragma unroll
        for (int jp = 0; jp < 2; jp++) {
          const int colL = wn * 64 + jp * 16 + (lane & 15);  // (colL&63) < 32
          const int d = colL & 63;
          const float c = cs[d], sn = sns[d];  // == cs[d+32], sns[d+32]
          const float xlo = acc[i][jp][r], xhi = acc[i][jp + 2][r];
          Obuf[rowL][colL]      = f2bf((xlo * c - xhi * sn) * qscale);
          Obuf[rowL][colL + 32] = f2bf((xhi * c + xlo * sn) * qscale);
        }
      }
    __syncthreads();
#pragma unroll
    for (int it = 0; it < 4; it++) {
      const int t = tid + it * 512;       // 0..2047 16B chunks
      const int d8 = t & 7, sl = (t >> 3) & 127, hl = t >> 10;
      *(short8*)(dst + ((size_t)(b * kH + h0 + hl) * kS + s0 + sl) * kD + d8 * 8) =
          *(const short8*)&Obuf[sl][hl * 64 + d8 * 8];
    }
  }
}

// ---------------------------------------------------------------------------
// GEMM2 (R13-exact): C fp32 = A @ B^T (bf16 in), 4 waves, 128x64 tile
// (768 blocks = 3/CU), simple 2-barrier K64 loop. Wave sub-tile 64x32.
// ---------------------------------------------------------------------------
__global__ __launch_bounds__(256) void gemm_bf16_nt(
    const unsigned short* __restrict__ A, const unsigned short* __restrict__ B,
    float* __restrict__ C, int M, int N, int K) {
  __shared__ unsigned short As[128 * 64];  // 16 KB
  __shared__ unsigned short Bs[64 * 64];   // 8 KB

  const int tid = threadIdx.x;
  const int lane = tid & 63;
  const int wave = tid >> 6;
  const int l15 = lane & 15;
  const int m0 = blockIdx.x * 128;
  const int n0 = blockIdx.y * 64;

  int ldsA[4];
  const unsigned short* gA[4];
#pragma unroll
  for (int t = 0; t < 4; t++) {
    const int ci = (wave * 4 + t) * 64 + lane;   // 0..1023
    const int row = ci >> 3;
    const int c = (ci & 7) ^ (row & 7);
    ldsA[t] = ci * 8;
    gA[t] = A + (size_t)(m0 + row) * K + c * 8;
  }
  int ldsB[2];
  const unsigned short* gB[2];
#pragma unroll
  for (int t = 0; t < 2; t++) {
    const int ci = (wave * 2 + t) * 64 + lane;   // 0..511
    const int row = ci >> 3;                     // 0..63
    const int c = (ci & 7) ^ (row & 7);
    ldsB[t] = ci * 8;
    gB[t] = B + (size_t)(n0 + row) * K + c * 8;
  }

  const int wm = wave >> 1, wn = wave & 1;
  const int mr = wm * 64 + l15;
  const int nr = wn * 32 + l15;
  const int kq = lane >> 4;

  floatx4 acc[4][2];
#pragma unroll
  for (int i = 0; i < 4; i++)
#pragma unroll
    for (int j = 0; j < 2; j++) acc[i][j] = (floatx4)(0.f);

  for (int k0 = 0; k0 < K; k0 += 64) {
    if (k0) __syncthreads();
#pragma unroll
    for (int t = 0; t < 4; t++) gload_lds16(gA[t] + k0, &As[ldsA[t]]);
#pragma unroll
    for (int t = 0; t < 2; t++) gload_lds16(gB[t] + k0, &Bs[ldsB[t]]);
    __syncthreads();
#pragma unroll
    for (int s = 0; s < 2; s++) {
      short8 af[4], bf[2];
#pragma unroll
      for (int i = 0; i < 4; i++)
        af[i] = *(const short8*)&As[(mr + i * 16) * 64 + (((s * 4 + kq) ^ ((mr + i * 16) & 7)) * 8)];
#pragma unroll
      for (int j = 0; j < 2; j++)
        bf[j] = *(const short8*)&Bs[(nr + j * 16) * 64 + (((s * 4 + kq) ^ ((nr + j * 16) & 7)) * 8)];
#pragma unroll
      for (int i = 0; i < 4; i++)
#pragma unroll
        for (int j = 0; j < 2; j++)
          acc[i][j] = __builtin_amdgcn_mfma_f32_16x16x32_bf16(af[i], bf[j],
                                                              acc[i][j], 0, 0, 0);
    }
  }

  const int crow = m0 + wm * 64 + kq * 4;
  const int ccol = n0 + wn * 32 + l15;
#pragma unroll
  for (int i = 0; i < 4; i++)
#pragma unroll
    for (int r = 0; r < 4; r++) {
      float* cp = C + (size_t)(crow + i * 16 + r) * N + ccol;
#pragma unroll
      for (int j = 0; j < 2; j++) cp[j * 16] = acc[i][j][r];
    }
}

// ---------------------------------------------------------------------------
// Attention v5: AQT=64 queries, 192 keys per block, 4 waves = (tq, kh/dh).
// Swapped QK^T (mfma(K,Q)): C row=key, col=query -> each lane holds 4
// consecutive keys for ONE query. P stored into plain [qgrp][query][key]
// tile (one b64 store per (qs,g)); row-sum = 2 shfl_xor per qs; PV A-frags
// read as 2x b64. Out staged through LDS -> 16B coalesced stores.
// ---------------------------------------------------------------------------
constexpr int AQT = 64;

__global__ __launch_bounds__(256) void attn_v5(
    const unsigned short* __restrict__ Qr, const unsigned short* __restrict__ Kr,
    const unsigned short* __restrict__ Vt, unsigned short* __restrict__ out) {
  __shared__ unsigned short P2[4][16][200];  // 25.6 KB (pad 192->200)
  __shared__ float Ssum[2][AQT];

  const int tid = threadIdx.x;
  const int lane = tid & 63;
  const int wave = tid >> 6;
  const int quad = lane >> 4;
  const int l15 = lane & 15;
  const int qbase = blockIdx.x * AQT;
  const int h = blockIdx.y, b = blockIdx.z;
  const int bh = b * kH + h;
  const int kbase = qbase - 64;
  const int tq = wave >> 1;  // 0,1: query half (32 rows)
  const int kh = wave & 1;   // QK^T: key-half (96 keys). PV: d-half (32 cols).

  // ---- Q A-frags: 2 query sub-tiles x (lo,hi) ----
  short8 a0[2], a1[2];
#pragma unroll
  for (int qs = 0; qs < 2; qs++) {
    const unsigned short* qsrc =
        Qr + ((size_t)bh * kS + qbase + tq * 32 + qs * 16 + l15) * kD + quad * 8;
    a0[qs] = *(const short8*)qsrc;
    a1[qs] = *(const short8*)(qsrc + 32);
  }

  // ---- K frags (clamped) + SWAPPED QK^T MFMA: acc[qs][g], row=key ----
  floatx4 acc[2][6];
  const unsigned short* ksrc = Kr + (size_t)bh * kS * kD;
#pragma unroll
  for (int g = 0; g < 6; g++) {
    int row = kbase + (kh * 6 + g) * 16 + l15;
    row = min(max(row, 0), kS - 1);
    const unsigned short* kp = ksrc + (size_t)row * kD + quad * 8;
    const short8 b0 = *(const short8*)kp;
    const short8 b1 = *(const short8*)(kp + 32);
#pragma unroll
    for (int qs = 0; qs < 2; qs++) {
      floatx4 z = (floatx4)(0.f);
      z = __builtin_amdgcn_mfma_f32_16x16x32_bf16(b0, a0[qs], z, 0, 0, 0);
      z = __builtin_amdgcn_mfma_f32_16x16x32_bf16(b1, a1[qs], z, 0, 0, 0);
      acc[qs][g] = z;   // acc[qs][g][r]: key=(kh*6+g)*16+quad*4+r, query=l15
    }
  }

  // ---- V^T B-frags from global (issue while exp runs) ----
  short8 vf[2][6];
  {
    const unsigned short* vbase = Vt + (size_t)bh * kD * kS;
#pragma unroll
    for (int nt = 0; nt < 2; nt++) {
      const unsigned short* vrow = vbase + (size_t)(kh * 32 + nt * 16 + l15) * kS;
#pragma unroll
      for (int kk = 0; kk < 6; kk++) {
        int s0 = kbase + kk * 32 + quad * 8;
        s0 = min(max(s0, 0), kS - 8);  // chunk-aligned: garbage rows have P=0
        vf[nt][kk] = *(const short8*)(vrow + s0);
      }
    }
  }

  // ---- exp (no max-sub) + b64-packed P stores + 2-shfl row sums ----
#pragma unroll
  for (int qs = 0; qs < 2; qs++) {
    const int qloc = tq * 32 + qs * 16 + l15;   // local query of this lane
    float s = 0.f;
#pragma unroll
    for (int g = 0; g < 6; g++) {
      const int keyb = (kh * 6 + g) * 16 + quad * 4;  // first of 4 keys
      short4v pk;
#pragma unroll
      for (int r = 0; r < 4; r++) {
        const int key = keyb + r;
        const int kg_ = kbase + key;
        const bool valid = (key >= qloc) && (key <= qloc + 128) &&
                           (kg_ >= 0) && (kg_ < kS);
        const float e = valid ? __expf(acc[qs][g][r]) : 0.f;
        s += e;
        pk[r] = (short)f2bf(e);
      }
      *(short4v*)&P2[tq * 2 + qs][l15][keyb] = pk;   // one b64, 8B-aligned
    }
    s += __shfl_xor(s, 16, 64);   // reduce over quad (bits 4,5)
    s += __shfl_xor(s, 32, 64);
    if (lane < 16) Ssum[kh][tq * 32 + qs * 16 + lane] = s;
  }
  __syncthreads();

  // ---- PV MFMA: A-frags from P2 via 2x b64, B = preloaded vf ----
  floatx4 o[2][2];  // [qs][nt]
#pragma unroll
  for (int qs = 0; qs < 2; qs++)
#pragma unroll
    for (int nt = 0; nt < 2; nt++) o[qs][nt] = (floatx4)(0.f);
#pragma unroll
  for (int kk = 0; kk < 6; kk++) {
#pragma unroll
    for (int qs = 0; qs < 2; qs++) {
      const unsigned short* pp = &P2[tq * 2 + qs][l15][kk * 32 + quad * 8];
      union { short8 v8; short4v v4[2]; } u;
      u.v4[0] = *(const short4v*)pp;        // 8B-aligned (l15*400 ≡ 0 mod 8)
      u.v4[1] = *(const short4v*)(pp + 4);
      o[qs][0] = __builtin_amdgcn_mfma_f32_16x16x32_bf16(u.v8, vf[0][kk], o[qs][0], 0, 0, 0);
      o[qs][1] = __builtin_amdgcn_mfma_f32_16x16x32_bf16(u.v8, vf[1][kk], o[qs][1], 0, 0, 0);
    }
  }

  // ---- epilogue: normalize into LDS out-tile, then 16B coalesced stores ----
  __syncthreads();  // all waves done reading P2; reuse as Ob
  unsigned short (*Ob)[68] = (unsigned short (*)[68])P2;  // [64][68] pad
#pragma unroll
  for (int qs = 0; qs < 2; qs++)
#pragma unroll
    for (int r = 0; r < 4; r++) {
      const int q = tq * 32 + qs * 16 + quad * 4 + r;  // PV out: row=query
      const float inv = 1.f / (Ssum[0][q] + Ssum[1][q]);
      Ob[q][kh * 32 + l15] = f2bf(o[qs][0][r] * inv);
      Ob[q][kh * 32 + 16 + l15] = f2bf(o[qs][1][r] * inv);
    }
  __syncthreads();
#pragma unroll
  for (int it = 0; it < 2; it++) {
    const int t = tid + it * 256;          // 0..511: 64 rows x 8 chunks
    const int q = t >> 3, d8 = t & 7;
    *(short8*)(out + ((size_t)(b * kS + qbase + q)) * kHidden + h * kD + d8 * 8) =
        *(const short8*)&Ob[q][d8 * 8];
  }
}

// ---------------------------------------------------------------------------
extern "C" void kernel_launch(void* const* d_in, const int* in_sizes, int n_in,
                              void* d_out, int out_size, void* d_ws,
                              size_t ws_size, hipStream_t stream) {
  const float* hidden = (const float*)d_in[0];
  const float* cosp = (const float*)d_in[1];
  const float* sinp = (const float*)d_in[2];
  // d_in[3]: attention_mask — deterministic sliding-window mask, not read.
  const float* wqkv = (const float*)d_in[4];
  const float* wo = (const float*)d_in[5];
  float* out = (float*)d_out;

  const int M = kB * kS;  // 8192
  const size_t szH = (size_t)M * kHidden;

  unsigned short* hbf = (unsigned short*)d_ws;
  unsigned short* wqkvbf = hbf + szH;
  unsigned short* wobf = wqkvbf + (size_t)kQKV * kHidden;
  unsigned short* attnbf = wobf + (size_t)kHidden * kHidden;
  unsigned short* Qrb = attnbf + szH;
  unsigned short* Krb = Qrb + szH;
  unsigned short* Vtb = Krb + szH;

  const int ncvt = (M * kHidden + kQKV * kHidden + kHidden * kHidden) / 4;
  cvt_all<<<(ncvt + 255) / 256, 256, 0, stream>>>(hidden, wqkv, wo, hbf,
                                                  wqkvbf, wobf);

  dim3 g1(M / 128, kQKV / 128);
  gemm_qkv<<<g1, 512, 0, stream>>>(hbf, wqkvbf, cosp, sinp, Qrb, Krb, Vtb);

  dim3 ga(kS / AQT, kH, kB);
  attn_v5<<<ga, 256, 0, stream>>>(Qrb, Krb, Vtb, attnbf);

  dim3 g2(M / 128, kHidden / 64);
  gemm_bf16_nt<<<g2, 256, 0, stream>>>(attnbf, wobf, out, M, kHidden, kHidden);
}